// Round 9
// baseline (99.729 us; speedup 1.0000x reference)
//
#include <hip/hip_runtime.h>
#include <math.h>

#define NTX 3
#define NAX 2048
#define NEL 128
#define NPIX (512*256)
#define WIN 96                      // dwords per (el,t) window; max usable rel = 94
#define LDS_DW (NEL*3*WIN)
#define LDS_BYTES ((LDS_DW + NEL*3) * 4)

// FS / SOUND_SPEED
constexpr float DELAY_SCALE = 20000000.0f / 1540.0f;
constexpr float PITCH = 0.0003f;

typedef _Float16 half2_t __attribute__((ext_vector_type(2)));

__device__ __forceinline__ void glds4(const void* g, void* l) {
  __builtin_amdgcn_global_load_lds(
      (const __attribute__((address_space(1))) void*)g,
      (__attribute__((address_space(3))) void*)l, 4, 0, 0);
}

// Build pairs[t][el][ax] = (data[t][ax][el], data[t][ax+1][el]) as half2 (4 B).
__global__ __launch_bounds__(256) void make_pairs_k(const float* __restrict__ in,
                                                    half2_t* __restrict__ out) {
  __shared__ float tile[33][33];
  const int t = blockIdx.z;
  const int ax0 = blockIdx.x * 32;
  const int el0 = blockIdx.y * 32;
  const float* inp = in + (size_t)t * (NAX * NEL);
  half2_t* outp = out + (size_t)t * (NEL * NAX);
  const int lx = threadIdx.x;
  const int ly = threadIdx.y;
#pragma unroll
  for (int i = 0; i < 40; i += 8) {
    const int r = ly + i;
    if (r < 33) {
      const int ax = ax0 + r > NAX - 1 ? NAX - 1 : ax0 + r;
      tile[r][lx] = inp[(size_t)ax * NEL + (el0 + lx)];
    }
  }
  __syncthreads();
#pragma unroll
  for (int i = 0; i < 32; i += 8) {
    const int e = ly + i;
    half2_t p;
    p.x = (_Float16)tile[lx][e];
    p.y = (_Float16)tile[lx + 1][e];
    outp[(size_t)(el0 + e) * NAX + (ax0 + lx)] = p;
  }
}

// LDS window-staged DAS. Block = 512 thr (8 waves) on a 32x * 16z pixel tile.
// Phase A: per-(el,t) window base = floor(scale*min_tile_delay)-2 (exact lower
// bound: delay is z-monotone; x-min at clamped stationary point of convex g).
// Phase B: stage [base, base+95] of the fp16-pair array into LDS (coalesced
// global_load_lds; linear dst = uniform + lane*4).
// Phase C: per-lane lerp gathers from LDS (no L1 misses). Active-lane window
// bound: rel <= 3 + [2*dz + (|sin|+dx/r)*dxspan]*scale <= ~80 < 94 all bands.
__global__ __launch_bounds__(512, 2) void das_lds_k(const half2_t* __restrict__ pairs,
                                                    const float* __restrict__ grid,
                                                    const float* __restrict__ probe,
                                                    const float* __restrict__ angles,
                                                    float* __restrict__ out) {
  extern __shared__ unsigned s_dyn[];
  unsigned* s_win = s_dyn;                 // [NEL*3][WIN]
  int* s_base = (int*)(s_dyn + LDS_DW);    // [NEL*3] (el*3+t)

  const int tid = threadIdx.x;
  const int lane = tid & 63;
  const int wv = tid >> 6;
  const int x0i = (blockIdx.x & 7) * 32;   // 8 x-tiles
  const int z0i = (blockIdx.x >> 3) * 16;  // 32 z-bands

  const float xlo = grid[3 * x0i];
  const float xhi = grid[3 * (x0i + 31)];
  const float zlo = grid[3 * (z0i * 256) + 2];
  const float zhi = grid[3 * ((z0i + 15) * 256) + 2];

  // Phase A: window bases.
  if (tid < NEL * 3) {
    const int t = tid >> 7;
    const int el = tid & 127;
    const float a = angles[t];
    const float s = sinf(a), c = cosf(a);
    const float ex = ((float)el - 63.5f) * PITCH;
    const float xstar = ex - zlo * (s / c);           // unconstrained argmin
    const float xm = fminf(fmaxf(xstar, xlo), xhi);
    const float dxm = xm - ex;
    const float fmin = xm * s + zlo * c + sqrtf(fmaf(dxm, dxm, zlo * zlo));
    int b = (int)floorf(fmin * DELAY_SCALE) - 2;
    s_base[el * 3 + t] = b < 0 ? 0 : b;
  }
  __syncthreads();

  // Block-uniform active el range (conservative; per-lane mask below is exact).
  const float hapmax = zhi * 0.5f;
  const float inv_pitch = 1.0f / PITCH;
  int lo = (int)floorf((xlo - hapmax) * inv_pitch + 63.5f) - 1;
  int hi = (int)ceilf((xhi + hapmax) * inv_pitch + 63.5f) + 1;
  lo = lo < 0 ? 0 : lo;
  hi = hi > NEL - 1 ? NEL - 1 : hi;

  // Phase B: stage windows for el in [lo,hi], all tx.
  const unsigned* pairs_dw = (const unsigned*)pairs;
  const int ldsbase = lo * (3 * WIN);
  const int total = (hi - lo + 1) * 3 * WIN;
  for (int ib = 0; ib < total; ib += 512) {
    const int idx = ib + tid;
    if (idx < total) {
      const int winj = idx / WIN;          // const-div
      const int k = idx - winj * WIN;
      const int elOff = winj / 3;          // const-div
      const int t = winj - elOff * 3;
      const int elA = lo + elOff;
      const int sb = s_base[elA * 3 + t];
      const unsigned srcdw = ((unsigned)((t << 7) + elA) << 11) + (unsigned)(sb + k);
      // dst: wave-uniform base; HW adds lane*4.
      glds4(pairs_dw + srcdw, (void*)(s_win + ldsbase + ib + wv * 64));
    }
  }
  asm volatile("s_waitcnt vmcnt(0)" ::: "memory");
  __syncthreads();

  // Phase C: per-lane pixel, full el range, LDS gathers.
  const int xg = x0i + (lane & 31);
  const int zg = z0i + wv * 2 + (lane >> 5);
  const int pix = zg * 256 + xg;
  const float px = grid[3 * pix];
  const float pz = grid[3 * pix + 2];
  const float z2 = pz * pz;
  const float hap = pz * 0.5f;             // (z/F#)/2, F#=1 (exact vs ref)

  float wtx[NTX];
#pragma unroll
  for (int t = 0; t < NTX; ++t) {
    const float a = angles[t];
    wtx[t] = (px * sinf(a) + pz * cosf(a)) * DELAY_SCALE;
  }

  float acc = 0.0f;
#pragma unroll 2
  for (int el = lo; el <= hi; ++el) {
    const float ex = ((float)el - 63.5f) * PITCH;  // == probe x (bitwise)
    const float dx = px - ex;
    const bool act = fabsf(dx) <= hap;             // exact ref mask
    const float drx = sqrtf(fmaf(dx, dx, z2)) * DELAY_SCALE;
    const int eb = el * 3;
#pragma unroll
    for (int t = 0; t < NTX; ++t) {
      const float w = drx + wtx[t];
      int i0 = (int)w;                    // trunc == floor after 0-clamp
      i0 = i0 < 0 ? 0 : i0;
      int rel = i0 - s_base[eb + t];      // broadcast LDS read (uniform addr)
      rel = act ? rel : 0;                // masked lanes: safe in-window idx
      const unsigned pd0 = s_win[(eb + t) * WIN + rel];
      const unsigned pd = act ? pd0 : 0u; // masked -> exact 0 contribution
      const float f1 = w - (float)i0;     // == w - d0f
      const half2_t wh = __builtin_bit_cast(
          half2_t, __builtin_amdgcn_cvt_pkrtz(1.0f - f1, f1));
      acc = __builtin_amdgcn_fdot2(wh, __builtin_bit_cast(half2_t, pd), acc, false);
    }
  }
  out[pix] = acc;
}

// ---- R7 fallback (no dynamic-LDS opt-in): scattered-gather version ----
template <int B>
__device__ __forceinline__ void das_batch(int el, const half2_t* pairs,
                                          float px, float pz, float z2,
                                          float half_ap, const float* wtx,
                                          float& acc) {
  unsigned pd[B][NTX];
  float f1[B][NTX];
  bool act[B];
#pragma unroll
  for (int j = 0; j < B; ++j) {
    const int elu = __builtin_amdgcn_readfirstlane(el + j);
    const float ex = ((float)elu - 63.5f) * PITCH;
    const float dx = px - ex;
    act[j] = fabsf(dx) <= half_ap;
    const float drx = sqrtf(fmaf(dx, dx, z2)) * DELAY_SCALE;
    const unsigned* colu = (const unsigned*)(pairs + ((size_t)elu << 11));
#pragma unroll
    for (int t = 0; t < NTX; ++t) {
      const float w = drx + wtx[t];
      int i0 = (int)w;
      i0 = i0 < 0 ? 0 : i0;
      pd[j][t] = colu[(t << 18) + i0];
      f1[j][t] = w - (float)i0;
    }
  }
#pragma unroll
  for (int j = 0; j < B; ++j)
#pragma unroll
    for (int t = 0; t < NTX; ++t) {
      const unsigned pdv = act[j] ? pd[j][t] : 0u;
      const half2_t wh = __builtin_bit_cast(
          half2_t, __builtin_amdgcn_cvt_pkrtz(1.0f - f1[j][t], f1[j][t]));
      acc = __builtin_amdgcn_fdot2(wh, __builtin_bit_cast(half2_t, pdv), acc, false);
    }
}

__global__ __launch_bounds__(256, 8) void das_t_k(const half2_t* __restrict__ pairs,
                                                  const float* __restrict__ grid,
                                                  const float* __restrict__ probe,
                                                  const float* __restrict__ angles,
                                                  float* __restrict__ out) {
  __shared__ float s_part[256];
  const int tid = threadIdx.x;
  const int lane = tid & 63;
  const int wv = tid >> 6;
  const int x = (blockIdx.x & 15) * 16 + (lane & 15);
  const int z = (blockIdx.x >> 4) * 4 + (lane >> 4);
  const int pix = z * 256 + x;

  const float px = grid[3 * pix + 0];
  const float pz = grid[3 * pix + 2];
  const float z2 = pz * pz;
  const float half_ap = pz * 0.5f;

  float wtx[NTX];
#pragma unroll
  for (int t = 0; t < NTX; ++t) {
    const float a = angles[t];
    wtx[t] = (px * sinf(a) + pz * cosf(a)) * DELAY_SCALE;
  }

  const float inv_pitch = 1.0f / PITCH;
  const int el_lo = (int)floorf((px - half_ap) * inv_pitch + 63.5f) - 1;
  const int el_hi = (int)ceilf((px + half_ap) * inv_pitch + 63.5f) + 1;
  int lo = __shfl(el_lo, 48);
  int hi = __shfl(el_hi, 63);
  lo = lo < 0 ? 0 : lo;
  hi = hi > NEL - 1 ? NEL - 1 : hi;

  const int q = (hi - lo + 4) >> 2;
  const int e0 = lo + wv * q;
  int e1 = e0 + q - 1;
  e1 = e1 > hi ? hi : e1;

  float acc = 0.0f;
  int el = e0;
  for (; el + 3 <= e1; el += 4)
    das_batch<4>(el, pairs, px, pz, z2, half_ap, wtx, acc);
  for (; el <= e1; ++el)
    das_batch<1>(el, pairs, px, pz, z2, half_ap, wtx, acc);

  s_part[tid] = acc;
  __syncthreads();
  if (tid < 64) {
    out[pix] = s_part[tid] + s_part[tid + 64] + s_part[tid + 128] + s_part[tid + 192];
  }
}

// ---- no-workspace fallback ----
__global__ __launch_bounds__(256) void das_fb_k(const float* __restrict__ data,
                                                const float* __restrict__ grid,
                                                const float* __restrict__ probe,
                                                const float* __restrict__ angles,
                                                float* __restrict__ out) {
  __shared__ float s_ex[NEL];
  __shared__ float s_part[256];
  const int tid = threadIdx.x;
  if (tid < NEL) s_ex[tid] = probe[3 * tid];
  __syncthreads();
  const int pix = blockIdx.x * 64 + (tid & 63);
  const int chunk = tid >> 6;
  const float px = grid[3 * pix + 0];
  const float pz = grid[3 * pix + 2];
  const float z2 = pz * pz;
  const float half_ap = pz * 0.5f;
  float wtx[NTX];
#pragma unroll
  for (int t = 0; t < NTX; ++t) {
    const float a = angles[t];
    wtx[t] = (px * sinf(a) + pz * cosf(a)) * DELAY_SCALE;
  }
  float acc = 0.0f;
  const int el_begin = chunk * 32;
  for (int e = 0; e < 32; ++e) {
    const int el = el_begin + e;
    const float ex = s_ex[el];
    const float dx = px - ex;
    if (fabsf(dx) > half_ap) continue;
    const float base = sqrtf(fmaf(dx, dx, z2)) * DELAY_SCALE;
#pragma unroll
    for (int t = 0; t < NTX; ++t) {
      const float w = base + wtx[t];
      int i0 = (int)w;
      i0 = i0 < 0 ? 0 : i0;
      const float* colp = data + (size_t)t * (NAX * NEL) + el;
      const float s0 = colp[(size_t)i0 * NEL];
      const float s1 = colp[(size_t)(i0 + 1) * NEL];
      const float f1 = w - (float)i0;
      acc = fmaf(1.0f - f1, s0, fmaf(f1, s1, acc));
    }
  }
  s_part[tid] = acc;
  __syncthreads();
  if (tid < 64) {
    out[pix] = s_part[tid] + s_part[tid + 64] + s_part[tid + 128] + s_part[tid + 192];
  }
}

extern "C" void kernel_launch(void* const* d_in, const int* in_sizes, int n_in,
                              void* d_out, int out_size, void* d_ws, size_t ws_size,
                              hipStream_t stream) {
  const float* data = (const float*)d_in[0];    // (1, 3, 2048, 128, 1)
  const float* grid = (const float*)d_in[1];    // (131072, 3)
  const float* probe = (const float*)d_in[2];   // (128, 3)
  const float* angles = (const float*)d_in[3];  // (3,)
  float* out = (float*)d_out;                   // (1, 512, 256)

  const size_t pbytes = (size_t)NTX * NEL * NAX * sizeof(half2_t);  // 3 MB
  if (ws_size >= pbytes) {
    half2_t* pairs = (half2_t*)d_ws;
    dim3 tb(32, 8);
    dim3 tg(NAX / 32, NEL / 32, NTX);
    make_pairs_k<<<tg, tb, 0, stream>>>(data, pairs);
    hipError_t e = hipFuncSetAttribute(
        (const void*)das_lds_k, hipFuncAttributeMaxDynamicSharedMemorySize,
        LDS_BYTES);
    if (e == hipSuccess) {
      das_lds_k<<<256, 512, LDS_BYTES, stream>>>(pairs, grid, probe, angles, out);
    } else {
      das_t_k<<<NPIX / 64, 256, 0, stream>>>(pairs, grid, probe, angles, out);
    }
  } else {
    das_fb_k<<<NPIX / 64, 256, 0, stream>>>(data, grid, probe, angles, out);
  }
}

// Round 10
// 97.239 us; speedup vs baseline: 1.0256x; 1.0256x over previous
//
#include <hip/hip_runtime.h>
#include <math.h>

#define NTX 3
#define NAX 2048
#define NEL 128
#define NX 256
#define NZ 512
#define NPIX (NZ*NX)

// FS / SOUND_SPEED
constexpr float DELAY_SCALE = 20000000.0f / 1540.0f;
constexpr float PITCH = 0.0003f;

typedef _Float16 half2_t __attribute__((ext_vector_type(2)));

__device__ __forceinline__ void glds4(const void* g, void* l) {
  __builtin_amdgcn_global_load_lds(
      (const __attribute__((address_space(1))) void*)g,
      (__attribute__((address_space(3))) void*)l, 4, 0, 0);
}

// Build pairs[t][el][ax] = (data[t][ax][el], data[t][ax+1][el]) as half2 (4 B).
// 3 MB, L2-resident.
__global__ __launch_bounds__(256) void make_pairs_k(const float* __restrict__ in,
                                                    half2_t* __restrict__ out) {
  __shared__ float tile[33][33];
  const int t = blockIdx.z;
  const int ax0 = blockIdx.x * 32;
  const int el0 = blockIdx.y * 32;
  const float* inp = in + (size_t)t * (NAX * NEL);
  half2_t* outp = out + (size_t)t * (NEL * NAX);
  const int lx = threadIdx.x;
  const int ly = threadIdx.y;
#pragma unroll
  for (int i = 0; i < 40; i += 8) {
    const int r = ly + i;
    if (r < 33) {
      const int ax = ax0 + r > NAX - 1 ? NAX - 1 : ax0 + r;
      tile[r][lx] = inp[(size_t)ax * NEL + (el0 + lx)];
    }
  }
  __syncthreads();
#pragma unroll
  for (int i = 0; i < 32; i += 8) {
    const int e = ly + i;
    half2_t p;
    p.x = (_Float16)tile[lx][e];
    p.y = (_Float16)tile[lx + 1][e];
    outp[(size_t)(el0 + e) * NAX + (ax0 + lx)] = p;
  }
}

// Per-wave window-staged DAS.
// Block = 512 thr (8 waves), all on ONE 64x * 4z pixel tile (256 px); the 8
// waves split the active-el range. Per (el,t): stage a 128-dword window of the
// pair array into this wave's LDS slot via 2 coalesced global_load_lds
// (consecutive-el windows overlap ~95% -> L1 hits), then the 12 lerp reads
// (4 z * 3 t per lane) are ds_read_b32 from LDS. El-wise double buffer,
// vmcnt(6); waves run fully independently (no barrier in the loop).
// Window coverage proof: active-lane span <= 81 (drx over active x, z-chunk)
// + 21.5 (wtx x-spread) + 3.7 (z) + 2 (base margin) ~ 108 < 127.
__global__ __launch_bounds__(512, 4) void das_lw_k(const half2_t* __restrict__ pairs,
                                                   const float* __restrict__ grid,
                                                   const float* __restrict__ probe,
                                                   const float* __restrict__ angles,
                                                   float* __restrict__ out) {
  __shared__ unsigned s_win[8][2][NTX][128];  // 24 KB [wave][buf][t][dw]
  __shared__ float s_red[8][4][64];           // 8 KB  [wave][z][x]
  const int tid = threadIdx.x;
  const int lane = tid & 63;
  const int wid = tid >> 6;
  const int x0 = (blockIdx.x & 3) * 64;
  const int z0 = (blockIdx.x >> 2) * 4;
  const int x = x0 + lane;

  const float px = grid[3 * (z0 * NX + x)];
  float pz[4], z2[4], hap[4];
#pragma unroll
  for (int j = 0; j < 4; ++j) {
    pz[j] = grid[3 * ((z0 + j) * NX + x) + 2];
    z2[j] = pz[j] * pz[j];
    hap[j] = pz[j] * 0.5f;  // (z/F#)/2, F# = 1 (exact vs ref)
  }

  float wtx[4][NTX];
#pragma unroll
  for (int t = 0; t < NTX; ++t) {
    const float a = angles[t];
    const float s = sinf(a), c = cosf(a);
#pragma unroll
    for (int j = 0; j < 4; ++j) wtx[j][t] = (px * s + pz[j] * c) * DELAY_SCALE;
  }
  float minwtx[NTX];
#pragma unroll
  for (int t = 0; t < NTX; ++t)  // wtx linear in px -> min at an endpoint lane
    minwtx[t] = fminf(__shfl(wtx[0][t], 0), __shfl(wtx[0][t], 63));
  const float xlo = __shfl(px, 0);
  const float xhi = __shfl(px, 63);

  // Conservative active-el range for the tile (per-lane mask below is exact).
  const float inv_pitch = 1.0f / PITCH;
  const int lo_l = (int)floorf((px - hap[3]) * inv_pitch + 63.5f) - 1;
  const int hi_l = (int)ceilf((px + hap[3]) * inv_pitch + 63.5f) + 1;
  int lo = __shfl(lo_l, 0);
  int hi = __shfl(hi_l, 63);
  lo = lo < 0 ? 0 : lo;
  hi = hi > NEL - 1 ? NEL - 1 : hi;

  // Split el range across the block's 8 waves.
  const int q = (hi - lo + 8) >> 3;
  const int e0 = lo + wid * q;
  int e1 = e0 + q - 1;
  e1 = e1 > hi ? hi : e1;

  float acc[4] = {0.f, 0.f, 0.f, 0.f};

  if (e0 <= e1) {
    int w0c[NTX], w0n[NTX];
    const float pz0 = pz[0];

    auto stage = [&](int el, int buf, int* w0) {
      const float ex = ((float)el - 63.5f) * PITCH;
      // lower bound of drx over the tile: clamped distance to [xlo,xhi] at z0
      const float dxc = fmaxf(0.f, fmaxf(xlo - ex, ex - xhi));
      const float mind = sqrtf(fmaf(dxc, dxc, pz0 * pz0));
#pragma unroll
      for (int t = 0; t < NTX; ++t) {
        int w0t = (int)floorf(fmaf(mind, DELAY_SCALE, minwtx[t])) - 2;
        w0t = w0t < 0 ? 0 : (w0t > NAX - 128 ? NAX - 128 : w0t);
        w0[t] = w0t;
        const unsigned* src = (const unsigned*)pairs + ((unsigned)((t << 7) + el) << 11) + w0t;
        glds4(src + lane, (void*)&s_win[wid][buf][t][0]);
        glds4(src + 64 + lane, (void*)&s_win[wid][buf][t][64]);
      }
    };

    stage(e0, 0, w0n);
#pragma unroll 1
    for (int el = e0; el <= e1; ++el) {
      const int cur = (el - e0) & 1;
#pragma unroll
      for (int t = 0; t < NTX; ++t) w0c[t] = w0n[t];
      if (el < e1) {
        stage(el + 1, cur ^ 1, w0n);
        asm volatile("s_waitcnt vmcnt(6)" ::: "memory");  // current el's 6 done
      } else {
        asm volatile("s_waitcnt vmcnt(0)" ::: "memory");
      }
      const float ex = ((float)el - 63.5f) * PITCH;  // == probe x (bitwise)
      const float dx = px - ex;
      const float adx = fabsf(dx);
#pragma unroll
      for (int j = 0; j < 4; ++j) {
        const bool act = adx <= hap[j];  // exact ref mask
        const float drx = sqrtf(fmaf(dx, dx, z2[j])) * DELAY_SCALE;
#pragma unroll
        for (int t = 0; t < NTX; ++t) {
          const float w = drx + wtx[j][t];
          int i0 = (int)w;                 // trunc == floor after 0-clamp
          i0 = i0 < 0 ? 0 : i0;
          int rel = i0 - w0c[t];           // active lanes: in [0,110]
          rel = rel < 0 ? 0 : (rel > 127 ? 127 : rel);  // inactive: safe idx
          unsigned pd = s_win[wid][cur][t][rel];
          pd = act ? pd : 0u;              // masked -> exact 0 contribution
          const float f1 = w - (float)i0;  // == w - d0f (exact)
          const half2_t wh = __builtin_bit_cast(
              half2_t, __builtin_amdgcn_cvt_pkrtz(1.0f - f1, f1));
          acc[j] = __builtin_amdgcn_fdot2(wh, __builtin_bit_cast(half2_t, pd),
                                          acc[j], false);
        }
      }
    }
  }

#pragma unroll
  for (int j = 0; j < 4; ++j) s_red[wid][j][lane] = acc[j];
  __syncthreads();
  if (tid < 256) {
    const int xl = tid & 63;
    const int j = tid >> 6;
    float s = 0.f;
#pragma unroll
    for (int wv = 0; wv < 8; ++wv) s += s_red[wv][j][xl];
    out[(z0 + j) * NX + x0 + xl] = s;
  }
}

// ---- no-workspace fallback ----
__global__ __launch_bounds__(256) void das_fb_k(const float* __restrict__ data,
                                                const float* __restrict__ grid,
                                                const float* __restrict__ probe,
                                                const float* __restrict__ angles,
                                                float* __restrict__ out) {
  __shared__ float s_ex[NEL];
  __shared__ float s_part[256];
  const int tid = threadIdx.x;
  if (tid < NEL) s_ex[tid] = probe[3 * tid];
  __syncthreads();
  const int pix = blockIdx.x * 64 + (tid & 63);
  const int chunk = tid >> 6;
  const float px = grid[3 * pix + 0];
  const float pz = grid[3 * pix + 2];
  const float z2 = pz * pz;
  const float half_ap = pz * 0.5f;
  float wtx[NTX];
#pragma unroll
  for (int t = 0; t < NTX; ++t) {
    const float a = angles[t];
    wtx[t] = (px * sinf(a) + pz * cosf(a)) * DELAY_SCALE;
  }
  float acc = 0.0f;
  const int el_begin = chunk * 32;
  for (int e = 0; e < 32; ++e) {
    const int el = el_begin + e;
    const float ex = s_ex[el];
    const float dx = px - ex;
    if (fabsf(dx) > half_ap) continue;
    const float base = sqrtf(fmaf(dx, dx, z2)) * DELAY_SCALE;
#pragma unroll
    for (int t = 0; t < NTX; ++t) {
      const float w = base + wtx[t];
      int i0 = (int)w;
      i0 = i0 < 0 ? 0 : i0;
      const float* colp = data + (size_t)t * (NAX * NEL) + el;
      const float s0 = colp[(size_t)i0 * NEL];
      const float s1 = colp[(size_t)(i0 + 1) * NEL];
      const float f1 = w - (float)i0;
      acc = fmaf(1.0f - f1, s0, fmaf(f1, s1, acc));
    }
  }
  s_part[tid] = acc;
  __syncthreads();
  if (tid < 64) {
    out[pix] = s_part[tid] + s_part[tid + 64] + s_part[tid + 128] + s_part[tid + 192];
  }
}

extern "C" void kernel_launch(void* const* d_in, const int* in_sizes, int n_in,
                              void* d_out, int out_size, void* d_ws, size_t ws_size,
                              hipStream_t stream) {
  const float* data = (const float*)d_in[0];    // (1, 3, 2048, 128, 1)
  const float* grid = (const float*)d_in[1];    // (131072, 3)
  const float* probe = (const float*)d_in[2];   // (128, 3)
  const float* angles = (const float*)d_in[3];  // (3,)
  float* out = (float*)d_out;                   // (1, 512, 256)

  const size_t pbytes = (size_t)NTX * NEL * NAX * sizeof(half2_t);  // 3 MB
  if (ws_size >= pbytes) {
    half2_t* pairs = (half2_t*)d_ws;
    dim3 tb(32, 8);
    dim3 tg(NAX / 32, NEL / 32, NTX);
    make_pairs_k<<<tg, tb, 0, stream>>>(data, pairs);
    das_lw_k<<<512, 512, 0, stream>>>(pairs, grid, probe, angles, out);
  } else {
    das_fb_k<<<NPIX / 64, 256, 0, stream>>>(data, grid, probe, angles, out);
  }
}